// Round 2
// baseline (176.223 us; speedup 1.0000x reference)
//
#include <hip/hip_runtime.h>

// VQ-VAE vector quantizer, MI355X gfx950 — round 6: barrier-free main loop.
//  K1 prep : W fp32 -> bf16 (wbf) + ||w||^2 (wn) + zero accumulators
//  K2 fused: stage z as bf16 in LDS (once), each wave owns a disjoint
//            256-code range x all 64 rows, B-fragments read DIRECTLY from
//            L2-resident wbf into registers (no LDS staging, no barriers),
//            cross-wave argmin merge, loss = sum(||z||^2) + sum(best)
//            (algebraic identity -> z never re-read), DMA-gather W rows,
//            transposed z_q write.
// LDS B-read amplification (2 MB/block) and 64 barriers/block eliminated.

#define DIM      256
#define NCODES   1024
#define SPB      1024
#define ZQ_ELEMS 8388608
#define NBLK     512       // 32768 rows / 64

typedef float f32x4  __attribute__((ext_vector_type(4)));
typedef short bf16x8 __attribute__((ext_vector_type(8)));
typedef short bf16x4 __attribute__((ext_vector_type(4)));

__device__ __forceinline__ short f2bf(float f) {
    union { float f; unsigned u; } v; v.f = f;
    unsigned r = v.u + 0x7FFFu + ((v.u >> 16) & 1u);   // RNE
    return (short)(r >> 16);
}

#define GLL16(g, l)                                                            \
    __builtin_amdgcn_global_load_lds(                                          \
        (const __attribute__((address_space(1))) void*)(g),                    \
        (__attribute__((address_space(3))) void*)(l), 16, 0, 0)

#define WAITV0 asm volatile("s_waitcnt vmcnt(0)" ::: "memory")

// ---------------- K1: prep ----------------
__global__ __launch_bounds__(256) void prep(const float* __restrict__ w,
                                            short* __restrict__ wbf,
                                            float* __restrict__ wn,
                                            float* __restrict__ acc,
                                            unsigned* __restrict__ done) {
    const int t = threadIdx.x, wv = t >> 6, l = t & 63;
    const int k = blockIdx.x * 4 + wv;          // one wave per code
    const float* wr = w + (size_t)k * DIM + 4 * l;
    f32x4 v = *(const f32x4*)wr;
    bf16x4 p;
    p[0] = f2bf(v[0]); p[1] = f2bf(v[1]); p[2] = f2bf(v[2]); p[3] = f2bf(v[3]);
    *(bf16x4*)(wbf + (size_t)k * DIM + 4 * l) = p;
    float s = v[0]*v[0] + v[1]*v[1] + v[2]*v[2] + v[3]*v[3];
#pragma unroll
    for (int off = 32; off; off >>= 1) s += __shfl_down(s, off);
    if (l == 0) wn[k] = s;
    if (blockIdx.x == 0 && t == 0) { *acc = 0.f; *done = 0u; }
}

// ---------------- K2: fused gemm+argmin+gather+loss ----------------
// LDS: smem union: zs bf16 [256 d][68] (34816 B, phases 1-2)
//                  zql fp32 64 rows x 1 KB (65536 B, phases 5-6)
// fixed tail: wnl f32[1024], barrv f32[256], barri i32[256], sidx i32[64],
//             zsq f32[4]
__global__ __launch_bounds__(256, 2) void vq_fused(const float* __restrict__ z,
                                                   const short* __restrict__ wbf,
                                                   const float* __restrict__ wn,
                                                   const float* __restrict__ w,
                                                   float* __restrict__ out,
                                                   float* __restrict__ acc,
                                                   unsigned* __restrict__ done) {
    __shared__ __align__(16) char smem[65536];
    __shared__ __align__(16) float wnl[NCODES];
    __shared__ float barrv[256];
    __shared__ int   barri[256];
    __shared__ int   sidx[64];
    __shared__ float zsq[4];

    short* zsb = (short*)smem;     // [256 d][stride 68]
    float* zql = (float*)smem;     // [64 s][256 dwords], s-rotated

    const int t   = threadIdx.x;
    const int wv  = t >> 6;
    const int l   = t & 63;
    const int n16 = l & 15;
    const int q   = l >> 4;
    const int sx  = t & 15;        // owns rows s = 4*sx .. 4*sx+3 (phases 1,6)
    const int c0  = t >> 4;        // channel group: c = c0 + 16*ci

    const int n0    = blockIdx.x * 64;
    const int batch = n0 >> 10;
    const int sbase = n0 & 1023;
    const float* zb = z   + (size_t)batch * DIM * SPB + sbase;
    float*       ob = out + (size_t)batch * DIM * SPB + sbase;

    // ---- phase 1: z -> LDS as bf16 (transposed [d][s]) + sum(z^2), wn -> LDS
    float lsq = 0.f;
#pragma unroll
    for (int ci = 0; ci < 16; ++ci) {
        const int c = c0 + 16 * ci;
        f32x4 v = *(const f32x4*)(zb + (size_t)c * SPB + 4 * sx);
        bf16x4 p;
        p[0] = f2bf(v[0]); p[1] = f2bf(v[1]); p[2] = f2bf(v[2]); p[3] = f2bf(v[3]);
        *(bf16x4*)&zsb[68 * c + 4 * sx] = p;
        lsq += v[0]*v[0] + v[1]*v[1] + v[2]*v[2] + v[3]*v[3];
    }
#pragma unroll
    for (int off = 32; off; off >>= 1) lsq += __shfl_down(lsq, off);
    if (l == 0) zsq[wv] = lsq;
    *(f32x4*)&wnl[4 * t] = *(const f32x4*)(wn + 4 * t);
    __syncthreads();                // zs + wnl + zsq visible to all waves

    // ---- phase 2: A fragments for ALL 64 rows (4 groups of 16)
    // frag lane (q,n16): row 16g+n16, dims 32T+8q+j. bank = 2-way free.
    bf16x8 af[4][8];
#pragma unroll
    for (int g = 0; g < 4; ++g)
#pragma unroll
        for (int T = 0; T < 8; ++T) {
            bf16x8 a;
#pragma unroll
            for (int j = 0; j < 8; ++j)
                a[j] = zsb[68 * (32 * T + 8 * q + j) + 16 * g + n16];
            af[g][T] = a;
        }
    // no barrier: from here each wave is independent until argmin merge

    // ---- phase 3: codes [256*wv, 256*wv+256), B direct from L2, no LDS.
    // Per half h (16 codes): 8 x global 16B loads, 32 MFMA, best update.
    const int kw = 256 * wv;
    const short* wrow = wbf + ((size_t)(kw + n16) << 8) + 8 * q;

    float best[4][4];
    int   bidx[4][4];
#pragma unroll
    for (int g = 0; g < 4; ++g)
#pragma unroll
        for (int r = 0; r < 4; ++r) { best[g][r] = 3.4e38f; bidx[g][r] = 0; }

#pragma unroll
    for (int h = 0; h < 16; ++h) {
        const short* hp = wrow + h * 4096;     // 16 codes x 256 dims
        bf16x8 b[8];
#pragma unroll
        for (int T = 0; T < 8; ++T) b[T] = *(const bf16x8*)(hp + 32 * T);
        f32x4 a0 = {0.f,0.f,0.f,0.f}, a1 = {0.f,0.f,0.f,0.f};
        f32x4 a2 = {0.f,0.f,0.f,0.f}, a3 = {0.f,0.f,0.f,0.f};
        __builtin_amdgcn_s_setprio(1);
#pragma unroll
        for (int T = 0; T < 8; ++T) {
            a0 = __builtin_amdgcn_mfma_f32_16x16x32_bf16(af[0][T], b[T], a0, 0, 0, 0);
            a1 = __builtin_amdgcn_mfma_f32_16x16x32_bf16(af[1][T], b[T], a1, 0, 0, 0);
            a2 = __builtin_amdgcn_mfma_f32_16x16x32_bf16(af[2][T], b[T], a2, 0, 0, 0);
            a3 = __builtin_amdgcn_mfma_f32_16x16x32_bf16(af[3][T], b[T], a3, 0, 0, 0);
        }
        __builtin_amdgcn_s_setprio(0);
        const int k  = kw + 16 * h + n16;
        const float wk = wnl[k];
#pragma unroll
        for (int r = 0; r < 4; ++r) {
            float d0 = wk - 2.f * a0[r];
            if (d0 < best[0][r]) { best[0][r] = d0; bidx[0][r] = k; }
            float d1 = wk - 2.f * a1[r];
            if (d1 < best[1][r]) { best[1][r] = d1; bidx[1][r] = k; }
            float d2 = wk - 2.f * a2[r];
            if (d2 < best[2][r]) { best[2][r] = d2; bidx[2][r] = k; }
            float d3 = wk - 2.f * a3[r];
            if (d3 < best[3][r]) { best[3][r] = d3; bidx[3][r] = k; }
        }
    }

    // ---- phase 4: argmin merge. Reduce over code-lanes (n16), then waves.
    float blktot = 0.f;
#pragma unroll
    for (int g = 0; g < 4; ++g)
#pragma unroll
        for (int r = 0; r < 4; ++r) {
            float bv = best[g][r];
            int   bi = bidx[g][r];
#pragma unroll
            for (int m = 1; m < 16; m <<= 1) {
                float ov = __shfl_xor(bv, m);
                int   oi = __shfl_xor(bi, m);
                if (ov < bv || (ov == bv && oi < bi)) { bv = ov; bi = oi; }
            }
            if (n16 == 0) {
                const int row = 16 * g + 4 * q + r;   // z-row within block
                barrv[64 * wv + row] = bv;
                barri[64 * wv + row] = bi;
            }
        }
    __syncthreads();

    if (t < 64) {                   // wave 0: final merge across 4 waves
        float bv = barrv[t];
        int   bi = barri[t];
#pragma unroll
        for (int w2 = 1; w2 < 4; ++w2) {
            float ov = barrv[64 * w2 + t];
            int   oi = barri[64 * w2 + t];
            if (ov < bv || (ov == bv && oi < bi)) { bv = ov; bi = oi; }
        }
        sidx[t] = bi;
        // sum(best) over 64 rows; + sum(z^2): loss = (both)/8.4M
        float rs = bv;
#pragma unroll
        for (int off = 32; off; off >>= 1) rs += __shfl_down(rs, off);
        if (t == 0) blktot = rs + zsq[0] + zsq[1] + zsq[2] + zsq[3];
    }
    __syncthreads();                // sidx ready; zs region now dead

    // ---- phase 5: DMA-gather selected code rows, rotated by (s>>2) granules
    // logical dword c of row s lands at phys dword (c + 4*(s>>2)) & 255
#pragma unroll
    for (int i = 0; i < 16; ++i) {
        const int s  = 16 * wv + i;
        const int ks = sidx[s];
        const float* src = w + (size_t)ks * DIM + 4 * ((l - (s >> 2)) & 63);
        GLL16(src, (char*)smem + s * 1024 + l * 16);
    }
    WAITV0;
    __syncthreads();

    // ---- phase 6: transposed z_q write (conflict-free: 2 lanes/bank)
#pragma unroll 4
    for (int ci = 0; ci < 16; ++ci) {
        const int c = c0 + 16 * ci;
        f32x4 qv;
#pragma unroll
        for (int r = 0; r < 4; ++r)
            qv[r] = zql[(4 * sx + r) * 256 + ((c + 4 * sx) & 255)];
        __builtin_nontemporal_store(qv, (f32x4*)(ob + (size_t)c * SPB + 4 * sx));
    }

    if (t == 0) {
        atomicAdd(acc, blktot);
        __threadfence();
        unsigned prev = atomicAdd(done, 1u);
        if (prev == NBLK - 1) {
            float val = atomicAdd(acc, 0.f) * (1.f / 8388608.f);
            out[ZQ_ELEMS]     = val;
            out[ZQ_ELEMS + 1] = val;
        }
    }
}

extern "C" void kernel_launch(void* const* d_in, const int* in_sizes, int n_in,
                              void* d_out, int out_size, void* d_ws, size_t ws_size,
                              hipStream_t stream) {
    const float* z = (const float*)d_in[0];
    const float* w = (const float*)d_in[1];
    float* out = (float*)d_out;

    char* ws = (char*)d_ws;
    short*    wbf  = (short*)ws;                   // 512 KB
    float*    wn   = (float*)(ws + 524288);        // 4 KB
    float*    acc  = (float*)(ws + 528384);
    unsigned* done = (unsigned*)(ws + 528388);

    prep<<<256, 256, 0, stream>>>(w, wbf, wn, acc, done);
    vq_fused<<<NBLK, 256, 0, stream>>>(z, wbf, wn, w, out, acc, done);
}

// Round 3
// 148.769 us; speedup vs baseline: 1.1845x; 1.1845x over previous
//
#include <hip/hip_runtime.h>

// VQ-VAE vector quantizer, MI355X gfx950 — round 7: round-6 structure with
// the register budget fixed.
//  Round-6 post-mortem: __launch_bounds__(256,2) let the compiler target
//  4 waves/EU -> 128 VGPRs -> af[4][8] spilled to scratch (1 KB/thread,
//  +128 MB WRITE / +67 MB FETCH). LDS caps occupancy at 2 waves/EU anyway.
//  Fix: amdgpu_waves_per_eu(2,2) pins the target -> 256-VGPR budget,
//  and h-loop unroll 2 (not 16) keeps peak pressure in budget.
//  K1 prep : W fp32 -> bf16 (wbf) + ||w||^2 (wn) + zero accumulators
//  K2 fused: stage z as bf16 in LDS (once), each wave owns a disjoint
//            256-code range x all 64 rows, B-fragments read DIRECTLY from
//            L2-resident wbf into registers (no LDS staging, no barriers),
//            cross-wave argmin merge, loss = sum(||z||^2) + sum(best),
//            DMA-gather W rows, transposed z_q write.

#define DIM      256
#define NCODES   1024
#define SPB      1024
#define ZQ_ELEMS 8388608
#define NBLK     512       // 32768 rows / 64

typedef float f32x4  __attribute__((ext_vector_type(4)));
typedef short bf16x8 __attribute__((ext_vector_type(8)));
typedef short bf16x4 __attribute__((ext_vector_type(4)));

__device__ __forceinline__ short f2bf(float f) {
    union { float f; unsigned u; } v; v.f = f;
    unsigned r = v.u + 0x7FFFu + ((v.u >> 16) & 1u);   // RNE
    return (short)(r >> 16);
}

#define GLL16(g, l)                                                            \
    __builtin_amdgcn_global_load_lds(                                          \
        (const __attribute__((address_space(1))) void*)(g),                    \
        (__attribute__((address_space(3))) void*)(l), 16, 0, 0)

#define WAITV0 asm volatile("s_waitcnt vmcnt(0)" ::: "memory")

// ---------------- K1: prep ----------------
__global__ __launch_bounds__(256) void prep(const float* __restrict__ w,
                                            short* __restrict__ wbf,
                                            float* __restrict__ wn,
                                            float* __restrict__ acc,
                                            unsigned* __restrict__ done) {
    const int t = threadIdx.x, wv = t >> 6, l = t & 63;
    const int k = blockIdx.x * 4 + wv;          // one wave per code
    const float* wr = w + (size_t)k * DIM + 4 * l;
    f32x4 v = *(const f32x4*)wr;
    bf16x4 p;
    p[0] = f2bf(v[0]); p[1] = f2bf(v[1]); p[2] = f2bf(v[2]); p[3] = f2bf(v[3]);
    *(bf16x4*)(wbf + (size_t)k * DIM + 4 * l) = p;
    float s = v[0]*v[0] + v[1]*v[1] + v[2]*v[2] + v[3]*v[3];
#pragma unroll
    for (int off = 32; off; off >>= 1) s += __shfl_down(s, off);
    if (l == 0) wn[k] = s;
    if (blockIdx.x == 0 && t == 0) { *acc = 0.f; *done = 0u; }
}

// ---------------- K2: fused gemm+argmin+gather+loss ----------------
// LDS: smem union: zs bf16 [256 d][68] (34816 B, phases 1-2)
//                  zql fp32 64 rows x 1 KB (65536 B, phases 5-6)
// fixed tail: wnl f32[1024], barrv f32[256], barri i32[256], sidx i32[64],
//             zsq f32[4]
__global__ __launch_bounds__(256)
__attribute__((amdgpu_waves_per_eu(2, 2)))
void vq_fused(const float* __restrict__ z,
              const short* __restrict__ wbf,
              const float* __restrict__ wn,
              const float* __restrict__ w,
              float* __restrict__ out,
              float* __restrict__ acc,
              unsigned* __restrict__ done) {
    __shared__ __align__(16) char smem[65536];
    __shared__ __align__(16) float wnl[NCODES];
    __shared__ float barrv[256];
    __shared__ int   barri[256];
    __shared__ int   sidx[64];
    __shared__ float zsq[4];

    short* zsb = (short*)smem;     // [256 d][stride 68]
    float* zql = (float*)smem;     // [64 s][256 dwords], s-rotated

    const int t   = threadIdx.x;
    const int wv  = t >> 6;
    const int l   = t & 63;
    const int n16 = l & 15;
    const int q   = l >> 4;
    const int sx  = t & 15;        // owns rows s = 4*sx .. 4*sx+3 (phases 1,6)
    const int c0  = t >> 4;        // channel group: c = c0 + 16*ci

    const int n0    = blockIdx.x * 64;
    const int batch = n0 >> 10;
    const int sbase = n0 & 1023;
    const float* zb = z   + (size_t)batch * DIM * SPB + sbase;
    float*       ob = out + (size_t)batch * DIM * SPB + sbase;

    // ---- phase 1: z -> LDS as bf16 (transposed [d][s]) + sum(z^2), wn -> LDS
    float lsq = 0.f;
#pragma unroll
    for (int ci = 0; ci < 16; ++ci) {
        const int c = c0 + 16 * ci;
        f32x4 v = *(const f32x4*)(zb + (size_t)c * SPB + 4 * sx);
        bf16x4 p;
        p[0] = f2bf(v[0]); p[1] = f2bf(v[1]); p[2] = f2bf(v[2]); p[3] = f2bf(v[3]);
        *(bf16x4*)&zsb[68 * c + 4 * sx] = p;
        lsq += v[0]*v[0] + v[1]*v[1] + v[2]*v[2] + v[3]*v[3];
    }
#pragma unroll
    for (int off = 32; off; off >>= 1) lsq += __shfl_down(lsq, off);
    if (l == 0) zsq[wv] = lsq;
    *(f32x4*)&wnl[4 * t] = *(const f32x4*)(wn + 4 * t);
    __syncthreads();                // zs + wnl + zsq visible to all waves

    // ---- phase 2: A fragments for ALL 64 rows (4 groups of 16)
    // frag lane (q,n16): row 16g+n16, dims 32T+8q+j. bank = 2-way free.
    bf16x8 af[4][8];
#pragma unroll
    for (int g = 0; g < 4; ++g)
#pragma unroll
        for (int T = 0; T < 8; ++T) {
            bf16x8 a;
#pragma unroll
            for (int j = 0; j < 8; ++j)
                a[j] = zsb[68 * (32 * T + 8 * q + j) + 16 * g + n16];
            af[g][T] = a;
        }
    // no barrier: from here each wave is independent until argmin merge

    // ---- phase 3: codes [256*wv, 256*wv+256), B direct from L2, no LDS.
    // Per half h (16 codes): 8 x global 16B loads, 32 MFMA, best update.
    const int kw = 256 * wv;
    const short* wrow = wbf + ((size_t)(kw + n16) << 8) + 8 * q;

    float best[4][4];
    int   bidx[4][4];
#pragma unroll
    for (int g = 0; g < 4; ++g)
#pragma unroll
        for (int r = 0; r < 4; ++r) { best[g][r] = 3.4e38f; bidx[g][r] = 0; }

#pragma unroll 2
    for (int h = 0; h < 16; ++h) {
        const short* hp = wrow + h * 4096;     // 16 codes x 256 dims
        bf16x8 b[8];
#pragma unroll
        for (int T = 0; T < 8; ++T) b[T] = *(const bf16x8*)(hp + 32 * T);
        f32x4 a0 = {0.f,0.f,0.f,0.f}, a1 = {0.f,0.f,0.f,0.f};
        f32x4 a2 = {0.f,0.f,0.f,0.f}, a3 = {0.f,0.f,0.f,0.f};
        __builtin_amdgcn_s_setprio(1);
#pragma unroll
        for (int T = 0; T < 8; ++T) {
            a0 = __builtin_amdgcn_mfma_f32_16x16x32_bf16(af[0][T], b[T], a0, 0, 0, 0);
            a1 = __builtin_amdgcn_mfma_f32_16x16x32_bf16(af[1][T], b[T], a1, 0, 0, 0);
            a2 = __builtin_amdgcn_mfma_f32_16x16x32_bf16(af[2][T], b[T], a2, 0, 0, 0);
            a3 = __builtin_amdgcn_mfma_f32_16x16x32_bf16(af[3][T], b[T], a3, 0, 0, 0);
        }
        __builtin_amdgcn_s_setprio(0);
        const int k  = kw + 16 * h + n16;
        const float wk = wnl[k];
#pragma unroll
        for (int r = 0; r < 4; ++r) {
            float d0 = wk - 2.f * a0[r];
            if (d0 < best[0][r]) { best[0][r] = d0; bidx[0][r] = k; }
            float d1 = wk - 2.f * a1[r];
            if (d1 < best[1][r]) { best[1][r] = d1; bidx[1][r] = k; }
            float d2 = wk - 2.f * a2[r];
            if (d2 < best[2][r]) { best[2][r] = d2; bidx[2][r] = k; }
            float d3 = wk - 2.f * a3[r];
            if (d3 < best[3][r]) { best[3][r] = d3; bidx[3][r] = k; }
        }
    }

    // ---- phase 4: argmin merge. Reduce over code-lanes (n16), then waves.
    float blktot = 0.f;
#pragma unroll
    for (int g = 0; g < 4; ++g)
#pragma unroll
        for (int r = 0; r < 4; ++r) {
            float bv = best[g][r];
            int   bi = bidx[g][r];
#pragma unroll
            for (int m = 1; m < 16; m <<= 1) {
                float ov = __shfl_xor(bv, m);
                int   oi = __shfl_xor(bi, m);
                if (ov < bv || (ov == bv && oi < bi)) { bv = ov; bi = oi; }
            }
            if (n16 == 0) {
                const int row = 16 * g + 4 * q + r;   // z-row within block
                barrv[64 * wv + row] = bv;
                barri[64 * wv + row] = bi;
            }
        }
    __syncthreads();

    if (t < 64) {                   // wave 0: final merge across 4 waves
        float bv = barrv[t];
        int   bi = barri[t];
#pragma unroll
        for (int w2 = 1; w2 < 4; ++w2) {
            float ov = barrv[64 * w2 + t];
            int   oi = barri[64 * w2 + t];
            if (ov < bv || (ov == bv && oi < bi)) { bv = ov; bi = oi; }
        }
        sidx[t] = bi;
        // sum(best) over 64 rows; + sum(z^2): loss = (both)/8.4M
        float rs = bv;
#pragma unroll
        for (int off = 32; off; off >>= 1) rs += __shfl_down(rs, off);
        if (t == 0) blktot = rs + zsq[0] + zsq[1] + zsq[2] + zsq[3];
    }
    __syncthreads();                // sidx ready; zs region now dead

    // ---- phase 5: DMA-gather selected code rows, rotated by (s>>2) granules
    // logical dword c of row s lands at phys dword (c + 4*(s>>2)) & 255
#pragma unroll
    for (int i = 0; i < 16; ++i) {
        const int s  = 16 * wv + i;
        const int ks = sidx[s];
        const float* src = w + (size_t)ks * DIM + 4 * ((l - (s >> 2)) & 63);
        GLL16(src, (char*)smem + s * 1024 + l * 16);
    }
    WAITV0;
    __syncthreads();

    // ---- phase 6: transposed z_q write (conflict-free: 2 lanes/bank)
#pragma unroll 4
    for (int ci = 0; ci < 16; ++ci) {
        const int c = c0 + 16 * ci;
        f32x4 qv;
#pragma unroll
        for (int r = 0; r < 4; ++r)
            qv[r] = zql[(4 * sx + r) * 256 + ((c + 4 * sx) & 255)];
        __builtin_nontemporal_store(qv, (f32x4*)(ob + (size_t)c * SPB + 4 * sx));
    }

    if (t == 0) {
        atomicAdd(acc, blktot);
        __threadfence();
        unsigned prev = atomicAdd(done, 1u);
        if (prev == NBLK - 1) {
            float val = atomicAdd(acc, 0.f) * (1.f / 8388608.f);
            out[ZQ_ELEMS]     = val;
            out[ZQ_ELEMS + 1] = val;
        }
    }
}

extern "C" void kernel_launch(void* const* d_in, const int* in_sizes, int n_in,
                              void* d_out, int out_size, void* d_ws, size_t ws_size,
                              hipStream_t stream) {
    const float* z = (const float*)d_in[0];
    const float* w = (const float*)d_in[1];
    float* out = (float*)d_out;

    char* ws = (char*)d_ws;
    short*    wbf  = (short*)ws;                   // 512 KB
    float*    wn   = (float*)(ws + 524288);        // 4 KB
    float*    acc  = (float*)(ws + 528384);
    unsigned* done = (unsigned*)(ws + 528388);

    prep<<<256, 256, 0, stream>>>(w, wbf, wn, acc, done);
    vq_fused<<<NBLK, 256, 0, stream>>>(z, wbf, wn, w, out, acc, done);
}